// Round 5
// baseline (392.606 us; speedup 1.0000x reference)
//
#include <hip/hip_runtime.h>
#include <stdint.h>

#define B_   8
#define D_   192      // Cin*3
#define N_   2048
#define KNb  11       // k+1

using u32 = uint32_t;
using u16 = unsigned short;
typedef _Float16 f16;
struct alignas(8) h4 { f16 x, y, z, w; };

typedef __attribute__((ext_vector_type(8)))  short short8;
typedef __attribute__((ext_vector_type(16))) float f32x16;

__device__ __forceinline__ float bf2f(u16 h){ union{u32 i; float f;} x; x.i = ((u32)h) << 16; return x.f; }
__device__ __forceinline__ u16 f2bf(float f){
  union{float f; u32 i;} x; x.f = f;
  u32 r = (x.i + 0x7fffu + ((x.i >> 16) & 1u)) >> 16;
  return (u16)r;
}
__device__ __forceinline__ u32 umax32(u32 a, u32 b){ return a > b ? a : b; }
__device__ __forceinline__ u32 umin32(u32 a, u32 b){ return a < b ? a : b; }

// ---------------- K0: bf16 fragment-page emit + fp32 transpose + f64 xx ----------------
// Xs layout: page P = (b*64 + tile)*12 + chunk, data[P][lane=lh*32+l31][8 shorts]
//   = bf16 of x[row = tile*32 + l31][d = chunk*16 + lh*8 + 0..8)].
// This is exactly the mfma_32x32x16_bf16 A/B fragment order -> knn loads are 1KB contiguous.
__global__ __launch_bounds__(256) void split_kernel(const float* __restrict__ x,
                                                    short* __restrict__ Xs,
                                                    float* __restrict__ xT,
                                                    double* __restrict__ xxd){
  __shared__ float A[D_ * 64];                       // 48 KB, [d][m]
  const int b = blockIdx.y, m0 = blockIdx.x * 64, t = threadIdx.x;
  const size_t xb = (size_t)b * D_ * N_;
  #pragma unroll
  for (int q = 0; q < 48; ++q){
    int p = t + 256*q;
    int d = p >> 6, i = p & 63;
    A[d*64 + i] = x[xb + (size_t)d*N_ + m0 + i];
  }
  __syncthreads();

  // bf16 fragment pages (hi only): 24 pages/block, wave-contiguous 1KB stores
  {
    const int l = t & 63, wv = t >> 6;
    const int lh = l >> 5, l31 = l & 31;
    #pragma unroll
    for (int j = 0; j < 6; ++j){
      int p  = j*4 + wv;                 // page within block 0..23
      int tt = p / 12, c = p % 12;       // tile, chunk
      int dbase = c*16 + lh*8;
      int row = tt*32 + l31;
      union{ u16 s[8]; int4 v; } u;
      #pragma unroll
      for (int q = 0; q < 8; ++q) u.s[q] = f2bf(A[(dbase + q)*64 + row]);
      size_t P = ((size_t)b*64 + blockIdx.x*2 + tt)*12 + c;
      *(int4*)(Xs + P*512 + l*8) = u.v;
    }
  }
  {
    const int m = t & 63, seg = t >> 6;
    float* trow = xT + ((size_t)b*N_ + m0 + m) * 192 + seg*48;
    #pragma unroll
    for (int j = 0; j < 12; ++j){
      float4 v = { A[(seg*48 + 4*j + 0)*64 + m], A[(seg*48 + 4*j + 1)*64 + m],
                   A[(seg*48 + 4*j + 2)*64 + m], A[(seg*48 + 4*j + 3)*64 + m] };
      *(float4*)(trow + 4*j) = v;
    }
  }
  if (t < 64){
    double s = 0.0;
    #pragma unroll 4
    for (int d = 0; d < D_; ++d){ double v = (double)A[d*64 + t]; s = fma(v, v, s); }
    xxd[b*N_ + m0 + t] = s;
  }
}

// ---------------- K1: MFMA kNN, 32-row stripes, fragment-page streaming ----------------
#define KLA   0         // 12,288 : A pages (12 x 1024)
#define KLCT  12288     // float[32*260] = 33,280 (aliased by merge keys)
#define KLXXS 45568     // 256 f32
#define KLXXN 46592     // 32 f32
#define KLSZ  46720
__global__ __launch_bounds__(512, 6) void knn_kernel(const short* __restrict__ Xs,
                                                     const double* __restrict__ xxd,
                                                     u16* __restrict__ cand){
  __shared__ __align__(16) char smem[KLSZ];
  float* CT  = (float*)(smem + KLCT);
  float* XXS = (float*)(smem + KLXXS);
  float* XXN = (float*)(smem + KLXXN);

  const int b = blockIdx.x, n0 = blockIdx.y * 32;
  const int t = threadIdx.x, lane = t & 63, w = t >> 6;
  const int l31 = lane & 31, lh = lane >> 5;

  // stage A (12 pages = query tile n0>>5), contiguous loads + linear LDS
  {
    const short* Ap = Xs + (((size_t)b*64 + (n0 >> 5)) * 12) * 512;
    #pragma unroll
    for (int j = 0; j < 2; ++j){
      int p = t + 512*j;                  // frag id 0..767
      if (j == 0 || t < 256){
        int4 v = *(const int4*)(Ap + (size_t)p*8);
        *(int4*)(smem + KLA + p*16) = v;
      }
    }
  }
  if (t < 32) XXN[t] = (float)xxd[b*N_ + n0 + t];

  u32 key[10];                                   // sorted ascending packed keys
  #pragma unroll
  for (int j = 0; j < 10; ++j) key[j] = 0u;

  for (int st = 0; st < 8; ++st){
    const int m0 = st * 256;
    __syncthreads();                             // prev selection done; A staged (st==0)
    if (t < 256) XXS[t] = (float)xxd[b*N_ + m0 + t];

    // wave w consumes neighbor tile (m0>>5)+w; pages are contiguous per wave
    const short* Bp = Xs + (((size_t)b*64 + (m0 >> 5) + w) * 12) * 512 + lane*8;
    short8 b0 = *(const short8*)(Bp + 0*512);
    short8 b1 = *(const short8*)(Bp + 1*512);
    short8 c0 = *(const short8*)(Bp + 2*512);
    short8 c1 = *(const short8*)(Bp + 3*512);
    short8 d0 = *(const short8*)(Bp + 4*512);
    short8 d1 = *(const short8*)(Bp + 5*512);
    f32x16 acc = (f32x16)0.0f;
    #pragma unroll
    for (int kc = 0; kc < 6; ++kc){
      short8 a0 = *(const short8*)(smem + KLA + (kc*2+0)*1024 + lane*16);
      short8 a1 = *(const short8*)(smem + KLA + (kc*2+1)*1024 + lane*16);
      acc = __builtin_amdgcn_mfma_f32_32x32x16_bf16(a0, b0, acc, 0, 0, 0);
      acc = __builtin_amdgcn_mfma_f32_32x32x16_bf16(a1, b1, acc, 0, 0, 0);
      b0 = c0; b1 = c1; c0 = d0; c1 = d1;
      if (kc < 3){
        d0 = *(const short8*)(Bp + (kc*2+6)*512);
        d1 = *(const short8*)(Bp + (kc*2+7)*512);
      }
    }

    #pragma unroll
    for (int reg = 0; reg < 16; ++reg){
      int r = (reg & 3) + 8*(reg >> 2) + 4*lh;
      CT[r*260 + w*32 + l31] = acc[reg];
    }
    __syncthreads();

    {
      const int r = t & 31, sub = t >> 5;
      const float xn = XXN[r];
      const float* ctp = CT + r*260 + sub*16;
      const float* xsp = XXS + sub*16;
      const int mb = m0 + sub*16;
      #pragma unroll
      for (int q = 0; q < 4; ++q){
        float4 cv = *(const float4*)(ctp + 4*q);
        float4 xv = *(const float4*)(xsp + 4*q);
        float vs[4]  = {cv.x, cv.y, cv.z, cv.w};
        float xs4[4] = {xv.x, xv.y, xv.z, xv.w};
        #pragma unroll
        for (int j = 0; j < 4; ++j){
          float v = fmaf(2.f, vs[j], -(xs4[j] + xn));
          u32 bbits = __float_as_uint(v);
          u32 kk = ((bbits ^ (u32)(((int)bbits >> 31) | 0x80000000)) & 0xFFFFF800u)
                   | (u32)(mb + 4*q + j);
          #pragma unroll
          for (int s = 0; s < 9; ++s) key[s] = umin32(key[s+1], umax32(kk, key[s]));
          key[9] = umax32(kk, key[9]);
        }
      }
    }
  }

  // merge 16 sorted lists x 10 per row -> top-16 window (static indexing only)
  __syncthreads();
  u32* MVK = (u32*)(smem + KLCT);                 // 16*32*10*4 = 20,480
  {
    const int r = t & 31, sub = t >> 5;
    #pragma unroll
    for (int j = 0; j < 10; ++j) MVK[(sub*32 + r)*10 + j] = key[j];
  }
  __syncthreads();
  if (t < 32){
    int head[16];
    #pragma unroll
    for (int q = 0; q < 16; ++q) head[q] = 9;
    const size_t ob = ((size_t)b*N_ + n0 + t) * 16;
    for (int s = 0; s < 16; ++s){
      u32 best = 0u; int bq = 0;
      #pragma unroll
      for (int q = 0; q < 16; ++q){
        int hh = head[q];
        u32 v = (hh >= 0) ? MVK[(q*32 + t)*10 + hh] : 0u;
        if (v > best){ best = v; bq = q; }
      }
      cand[ob + s] = (u16)(best & 2047u);
      #pragma unroll
      for (int q = 0; q < 16; ++q) head[q] -= (q == bq) ? 1 : 0;
    }
  }
}

// ---------------- K1b: f64 refine, register-only, shuffle-rank top-11 ----------------
__global__ __launch_bounds__(256) void refine_kernel(const float* __restrict__ xT,
                                                     const u16* __restrict__ cand,
                                                     const double* __restrict__ xxd,
                                                     int* __restrict__ idxout){
  const int wv = threadIdx.x >> 6, ln = threadIdx.x & 63;
  const int g = blockIdx.x * 4 + wv;               // 0..16383
  const int b = g >> 11, n = g & 2047;
  const int c = ln >> 2, part = ln & 3;
  const int m = (int)cand[(size_t)g*16 + c] & 2047;
  const float4* pn = (const float4*)(xT + ((size_t)b*N_ + n)*192 + part*48);
  const float4* pm = (const float4*)(xT + ((size_t)b*N_ + m)*192 + part*48);
  double s = 0.0;
  #pragma unroll
  for (int j = 0; j < 12; ++j){                    // d ascending: same f64 order as before
    float4 a = pn[j], bb = pm[j];
    s = fma((double)a.x, (double)bb.x, s);
    s = fma((double)a.y, (double)bb.y, s);
    s = fma((double)a.z, (double)bb.z, s);
    s = fma((double)a.w, (double)bb.w, s);
  }
  s += __shfl_down(s, 2, 64);
  s += __shfl_down(s, 1, 64);                      // part==0 lanes hold full dot
  double v = 2.0*s - xxd[b*N_ + n] - xxd[b*N_ + m];
  int rank = 0;
  #pragma unroll
  for (int q = 0; q < 16; ++q){
    double vq = __shfl(v, q*4, 64);
    int    mq = __shfl(m, q*4, 64);
    bool beat = (vq > v) || ((vq == v) && (mq < m));
    rank += beat ? 1 : 0;
  }
  if (part == 0 && rank < KNb)
    idxout[(size_t)g*KNb + rank] = m;
}

// ---------------- K2: P0/D0 from xT, role-split waves, 16-pt tiles ----------------
// R3 postmortem: launch_bounds(256,4) + 128-float weight arrays -> forced spill
// (VGPR 64, 400MB scratch traffic, 142us). Fix: halve the per-thread weight set by
// splitting roles across waves: waves 0-1 compute P only (wf), waves 2-3 compute D
// only (wd). 64 weight floats/thread -> ~100 VGPR natural, fits the (256,4) budget.
// Same fma ordering per output as R2 -> bitwise-identical results.
__global__ __launch_bounds__(256, 4) void project_kernel(const float* __restrict__ xT,
                                                         const float* __restrict__ Wf,
                                                         const float* __restrict__ Wd,
                                                         h4* __restrict__ P0h,
                                                         h4* __restrict__ D0h){
  __shared__ float A[16 * 192];                    // 12 KB, [m][e]
  const int b = blockIdx.x, m0 = blockIdx.y * 16, t = threadIdx.x;
  const int c = t & 63, g = t >> 6;
  const int role = g >> 1;                         // 0: feat(P), 1: dir(D)
  const int mg = g & 1;                            // point half: 8 points each

  const float* W = (role == 0) ? Wf : Wd;
  float wr[64];
  #pragma unroll
  for (int q = 0; q < 16; ++q){
    float4 u = *(const float4*)(W + c*64 + q*4);
    wr[q*4+0]=u.x; wr[q*4+1]=u.y; wr[q*4+2]=u.z; wr[q*4+3]=u.w;
  }
  {
    const float4* src = (const float4*)(xT + ((size_t)b*N_ + m0)*192);
    float4* dst = (float4*)A;
    #pragma unroll
    for (int j = 0; j < 3; ++j) dst[t + 256*j] = src[t + 256*j];
  }
  __syncthreads();

  for (int mi = 0; mi < 8; ++mi){
    int m = mg*8 + mi;
    const float4* row = (const float4*)(A + m*192);
    float p[3] = {0.f,0.f,0.f};
    #pragma unroll
    for (int v4 = 0; v4 < 48; ++v4){
      float4 f = row[v4];
      const int e = v4*4;
      p[(e+0)%3] = fmaf(wr[(e+0)/3], f.x, p[(e+0)%3]);
      p[(e+1)%3] = fmaf(wr[(e+1)/3], f.y, p[(e+1)%3]);
      p[(e+2)%3] = fmaf(wr[(e+2)/3], f.z, p[(e+2)%3]);
      p[(e+3)%3] = fmaf(wr[(e+3)/3], f.w, p[(e+3)%3]);
    }
    float ss = p[0]*p[0] + p[1]*p[1] + p[2]*p[2];
    size_t base = ((size_t)b*N_ + m0 + m)*64 + c;
    h4 v;
    v.x = (f16)p[0]; v.y = (f16)p[1]; v.z = (f16)p[2];
    if (role == 0){
      v.w = (f16)sqrtf(ss);
      P0h[base] = v;
    } else {
      v.w = (f16)ss;
      D0h[base] = v;
    }
  }
}

// ---------------- K3a: neighbor occurrence counts ----------------
__global__ __launch_bounds__(256) void count_kernel(const int* __restrict__ idxin, int* __restrict__ cnt){
  int i = blockIdx.x*256 + threadIdx.x;
  if (i < B_*N_*KNb){
    int b = i / (N_*KNb);
    atomicAdd(&cnt[b*N_ + (idxin[i] & 2047)], 1);
  }
}

// ---------------- K3b: per-channel weighted sum / sumsq of norms ----------------
__global__ __launch_bounds__(256) void stats_kernel(const h4* __restrict__ P0h,
                                                    const int* __restrict__ cnt,
                                                    float* __restrict__ gs){
  const int b = blockIdx.x >> 3;
  const int chunk = blockIdx.x & 7;
  const int w = threadIdx.x >> 6, c = threadIdx.x & 63;
  float s = 0.f, s2 = 0.f;
  const int mbase = chunk*256 + w*64;
  for (int i = 0; i < 64; ++i){
    int m = mbase + i;
    float wt = (float)cnt[b*N_ + m];
    float nv = (float)P0h[((size_t)b*N_ + m)*64 + c].w;
    s  = fmaf(wt, nv, s);
    s2 = fmaf(wt*nv, nv, s2);
  }
  __shared__ float red[8][64];
  red[w][c] = s; red[4+w][c] = s2;
  __syncthreads();
  if (w == 0) atomicAdd(&gs[c],    red[0][c]+red[1][c]+red[2][c]+red[3][c]);
  if (w == 1) atomicAdd(&gs[64+c], red[4][c]+red[5][c]+red[6][c]+red[7][c]);
}

// ---------------- K4: gather + BN + nonlinearity + mean over K ----------------
__global__ __launch_bounds__(512) void out_kernel(const h4* __restrict__ P0h, const h4* __restrict__ D0h,
                                                  const int* __restrict__ idxin, const float* __restrict__ gs,
                                                  const float* __restrict__ gamma, const float* __restrict__ beta,
                                                  float* __restrict__ outp){
  __shared__ float res[64 * 193];                  // 49,408 B
  const int b  = blockIdx.x;
  const int n0 = blockIdx.y * 64;
  const int t = threadIdx.x, w = t >> 6, c = t & 63;
  const float Ninv = 1.f / (float)(B_*N_*KNb);
  float mean = gs[c] * Ninv;
  float var  = gs[64+c] * Ninv - mean*mean;
  float istd = rsqrtf(var + 1e-5f);
  float sa = istd * gamma[c];
  float be = beta[c];
  const float kinv = 1.f/11.f;
  for (int i = 0; i < 8; ++i){
    int n = n0 + w*8 + i;
    const int* ip = idxin + ((size_t)b*N_ + n)*KNb;
    float a0=0, a1=0, a2=0;
    #pragma unroll
    for (int k = 0; k < KNb; ++k){
      int m = ip[k] & 2047;
      size_t base = ((size_t)b*N_ + m)*64 + c;
      h4 P  = P0h[base];
      h4 Dv = D0h[base];
      float pw = (float)P.w;
      float nb = (pw - mean)*sa + be;
      float sc = nb / pw;
      float p0 = (float)P.x*sc, p1 = (float)P.y*sc, p2 = (float)P.z*sc;
      float d0 = (float)Dv.x, d1 = (float)Dv.y, d2 = (float)Dv.z;
      float dot = p0*d0 + p1*d1 + p2*d2;
      float f = (dot >= 0.f) ? 0.f : dot / ((float)Dv.w + 1e-6f);
      a0 += p0 - f*d0; a1 += p1 - f*d1; a2 += p2 - f*d2;
    }
    int row = w*8 + i;
    res[row*193 + 3*c + 0] = a0*kinv;
    res[row*193 + 3*c + 1] = a1*kinv;
    res[row*193 + 3*c + 2] = a2*kinv;
  }
  __syncthreads();
  #pragma unroll
  for (int j = 0; j < 6; ++j){
    int p = t + 512*j;
    int cdim = p >> 4, nq = p & 15;
    float4 v = { res[(nq*4 + 0)*193 + cdim], res[(nq*4 + 1)*193 + cdim],
                 res[(nq*4 + 2)*193 + cdim], res[(nq*4 + 3)*193 + cdim] };
    *(float4*)(outp + ((size_t)b*192 + cdim)*N_ + n0 + nq*4) = v;
  }
}

extern "C" void kernel_launch(void* const* d_in, const int* in_sizes, int n_in,
                              void* d_out, int out_size, void* d_ws, size_t ws_size,
                              hipStream_t stream){
  const float* x     = (const float*)d_in[0];
  const float* Wf    = (const float*)d_in[1];
  const float* Wd    = (const float*)d_in[2];
  const float* gamma = (const float*)d_in[3];
  const float* beta  = (const float*)d_in[4];
  float* outp = (float*)d_out;

  char* ws = (char*)d_ws;
  int*    idx  = (int*)   (ws);                 // 720,896
  int*    cnt  = (int*)   (ws + 720896);        // 65,536
  float*  gs   = (float*) (ws + 786432);        // 512
  h4*     P0h  = (h4*)    (ws + 1048576);       // 8,388,608
  h4*     D0h  = (h4*)    (ws + 9437184);       // 8,388,608 (ends 17,825,792)
  short*  Xs   = (short*) (ws + 1048576);       //   alias (6,291,456), consumed pre-project
  double* xxd  = (double*)(ws + 13631488);      //   alias (lives in D0h region pre-project)
  u16*    cand = (u16*)   (ws + 13762560);      //   alias
  float*  xT   = (float*) (ws + 17825792);      // 12,582,912 (ends 30,408,704)

  hipMemsetAsync(cnt, 0, 66048, stream);        // zero cnt + gs (contiguous)
  split_kernel  <<<dim3(32, 8),  256, 0, stream>>>(x, Xs, xT, xxd);
  knn_kernel    <<<dim3(8, 64),  512, 0, stream>>>(Xs, xxd, cand);
  refine_kernel <<<4096,         256, 0, stream>>>(xT, cand, xxd, idx);
  project_kernel<<<dim3(8, 128), 256, 0, stream>>>(xT, Wf, Wd, P0h, D0h);
  count_kernel  <<<704,          256, 0, stream>>>(idx, cnt);
  stats_kernel  <<<64,           256, 0, stream>>>(P0h, cnt, gs);
  out_kernel    <<<dim3(8, 32),  512, 0, stream>>>(P0h, D0h, idx, gs, gamma, beta, outp);
}

// Round 6
// 295.406 us; speedup vs baseline: 1.3290x; 1.3290x over previous
//
#include <hip/hip_runtime.h>
#include <stdint.h>

#define B_   8
#define D_   192      // Cin*3
#define N_   2048
#define KNb  11       // k+1

using u32 = uint32_t;
using u16 = unsigned short;
typedef _Float16 f16;
struct alignas(8) h4 { f16 x, y, z, w; };

typedef __attribute__((ext_vector_type(8)))  short short8;
typedef __attribute__((ext_vector_type(16))) float f32x16;

__device__ __forceinline__ float bf2f(u16 h){ union{u32 i; float f;} x; x.i = ((u32)h) << 16; return x.f; }
__device__ __forceinline__ u16 f2bf(float f){
  union{float f; u32 i;} x; x.f = f;
  u32 r = (x.i + 0x7fffu + ((x.i >> 16) & 1u)) >> 16;
  return (u16)r;
}
__device__ __forceinline__ u32 umax32(u32 a, u32 b){ return a > b ? a : b; }
__device__ __forceinline__ u32 umin32(u32 a, u32 b){ return a < b ? a : b; }

// ---------------- K0: bf16 fragment-page emit + fp32 transpose + f64 xx ----------------
// Xs layout: page P = (b*64 + tile)*12 + chunk, data[P][lane=lh*32+l31][8 shorts]
//   = bf16 of x[row = tile*32 + l31][d = chunk*16 + lh*8 + 0..8)].
// This is exactly the mfma_32x32x16_bf16 A/B fragment order -> knn loads are 1KB contiguous.
__global__ __launch_bounds__(256) void split_kernel(const float* __restrict__ x,
                                                    short* __restrict__ Xs,
                                                    float* __restrict__ xT,
                                                    double* __restrict__ xxd){
  __shared__ float A[D_ * 64];                       // 48 KB, [d][m]
  const int b = blockIdx.y, m0 = blockIdx.x * 64, t = threadIdx.x;
  const size_t xb = (size_t)b * D_ * N_;
  #pragma unroll
  for (int q = 0; q < 48; ++q){
    int p = t + 256*q;
    int d = p >> 6, i = p & 63;
    A[d*64 + i] = x[xb + (size_t)d*N_ + m0 + i];
  }
  __syncthreads();

  // bf16 fragment pages (hi only): 24 pages/block, wave-contiguous 1KB stores
  {
    const int l = t & 63, wv = t >> 6;
    const int lh = l >> 5, l31 = l & 31;
    #pragma unroll
    for (int j = 0; j < 6; ++j){
      int p  = j*4 + wv;                 // page within block 0..23
      int tt = p / 12, c = p % 12;       // tile, chunk
      int dbase = c*16 + lh*8;
      int row = tt*32 + l31;
      union{ u16 s[8]; int4 v; } u;
      #pragma unroll
      for (int q = 0; q < 8; ++q) u.s[q] = f2bf(A[(dbase + q)*64 + row]);
      size_t P = ((size_t)b*64 + blockIdx.x*2 + tt)*12 + c;
      *(int4*)(Xs + P*512 + l*8) = u.v;
    }
  }
  {
    const int m = t & 63, seg = t >> 6;
    float* trow = xT + ((size_t)b*N_ + m0 + m) * 192 + seg*48;
    #pragma unroll
    for (int j = 0; j < 12; ++j){
      float4 v = { A[(seg*48 + 4*j + 0)*64 + m], A[(seg*48 + 4*j + 1)*64 + m],
                   A[(seg*48 + 4*j + 2)*64 + m], A[(seg*48 + 4*j + 3)*64 + m] };
      *(float4*)(trow + 4*j) = v;
    }
  }
  if (t < 64){
    double s = 0.0;
    #pragma unroll 4
    for (int d = 0; d < D_; ++d){ double v = (double)A[d*64 + t]; s = fma(v, v, s); }
    xxd[b*N_ + m0 + t] = s;
  }
}

// ---------------- K1: MFMA kNN, 32-row stripes, fragment-page streaming ----------------
#define KLA   0         // 12,288 : A pages (12 x 1024)
#define KLCT  12288     // float[32*260] = 33,280 (aliased by merge keys)
#define KLXXS 45568     // 256 f32
#define KLXXN 46592     // 32 f32
#define KLSZ  46720
__global__ __launch_bounds__(512, 6) void knn_kernel(const short* __restrict__ Xs,
                                                     const double* __restrict__ xxd,
                                                     u16* __restrict__ cand){
  __shared__ __align__(16) char smem[KLSZ];
  float* CT  = (float*)(smem + KLCT);
  float* XXS = (float*)(smem + KLXXS);
  float* XXN = (float*)(smem + KLXXN);

  const int b = blockIdx.x, n0 = blockIdx.y * 32;
  const int t = threadIdx.x, lane = t & 63, w = t >> 6;
  const int l31 = lane & 31, lh = lane >> 5;

  // stage A (12 pages = query tile n0>>5), contiguous loads + linear LDS
  {
    const short* Ap = Xs + (((size_t)b*64 + (n0 >> 5)) * 12) * 512;
    #pragma unroll
    for (int j = 0; j < 2; ++j){
      int p = t + 512*j;                  // frag id 0..767
      if (j == 0 || t < 256){
        int4 v = *(const int4*)(Ap + (size_t)p*8);
        *(int4*)(smem + KLA + p*16) = v;
      }
    }
  }
  if (t < 32) XXN[t] = (float)xxd[b*N_ + n0 + t];

  u32 key[10];                                   // sorted ascending packed keys
  #pragma unroll
  for (int j = 0; j < 10; ++j) key[j] = 0u;

  for (int st = 0; st < 8; ++st){
    const int m0 = st * 256;
    __syncthreads();                             // prev selection done; A staged (st==0)
    if (t < 256) XXS[t] = (float)xxd[b*N_ + m0 + t];

    // wave w consumes neighbor tile (m0>>5)+w; pages are contiguous per wave
    const short* Bp = Xs + (((size_t)b*64 + (m0 >> 5) + w) * 12) * 512 + lane*8;
    short8 b0 = *(const short8*)(Bp + 0*512);
    short8 b1 = *(const short8*)(Bp + 1*512);
    short8 c0 = *(const short8*)(Bp + 2*512);
    short8 c1 = *(const short8*)(Bp + 3*512);
    short8 d0 = *(const short8*)(Bp + 4*512);
    short8 d1 = *(const short8*)(Bp + 5*512);
    f32x16 acc = (f32x16)0.0f;
    #pragma unroll
    for (int kc = 0; kc < 6; ++kc){
      short8 a0 = *(const short8*)(smem + KLA + (kc*2+0)*1024 + lane*16);
      short8 a1 = *(const short8*)(smem + KLA + (kc*2+1)*1024 + lane*16);
      acc = __builtin_amdgcn_mfma_f32_32x32x16_bf16(a0, b0, acc, 0, 0, 0);
      acc = __builtin_amdgcn_mfma_f32_32x32x16_bf16(a1, b1, acc, 0, 0, 0);
      b0 = c0; b1 = c1; c0 = d0; c1 = d1;
      if (kc < 3){
        d0 = *(const short8*)(Bp + (kc*2+6)*512);
        d1 = *(const short8*)(Bp + (kc*2+7)*512);
      }
    }

    #pragma unroll
    for (int reg = 0; reg < 16; ++reg){
      int r = (reg & 3) + 8*(reg >> 2) + 4*lh;
      CT[r*260 + w*32 + l31] = acc[reg];
    }
    __syncthreads();

    {
      const int r = t & 31, sub = t >> 5;
      const float xn = XXN[r];
      const float* ctp = CT + r*260 + sub*16;
      const float* xsp = XXS + sub*16;
      const int mb = m0 + sub*16;
      #pragma unroll
      for (int q = 0; q < 4; ++q){
        float4 cv = *(const float4*)(ctp + 4*q);
        float4 xv = *(const float4*)(xsp + 4*q);
        float vs[4]  = {cv.x, cv.y, cv.z, cv.w};
        float xs4[4] = {xv.x, xv.y, xv.z, xv.w};
        #pragma unroll
        for (int j = 0; j < 4; ++j){
          float v = fmaf(2.f, vs[j], -(xs4[j] + xn));
          u32 bbits = __float_as_uint(v);
          u32 kk = ((bbits ^ (u32)(((int)bbits >> 31) | 0x80000000)) & 0xFFFFF800u)
                   | (u32)(mb + 4*q + j);
          #pragma unroll
          for (int s = 0; s < 9; ++s) key[s] = umin32(key[s+1], umax32(kk, key[s]));
          key[9] = umax32(kk, key[9]);
        }
      }
    }
  }

  // merge 16 sorted lists x 10 per row -> top-16 window (static indexing only)
  __syncthreads();
  u32* MVK = (u32*)(smem + KLCT);                 // 16*32*10*4 = 20,480
  {
    const int r = t & 31, sub = t >> 5;
    #pragma unroll
    for (int j = 0; j < 10; ++j) MVK[(sub*32 + r)*10 + j] = key[j];
  }
  __syncthreads();
  if (t < 32){
    int head[16];
    #pragma unroll
    for (int q = 0; q < 16; ++q) head[q] = 9;
    const size_t ob = ((size_t)b*N_ + n0 + t) * 16;
    for (int s = 0; s < 16; ++s){
      u32 best = 0u; int bq = 0;
      #pragma unroll
      for (int q = 0; q < 16; ++q){
        int hh = head[q];
        u32 v = (hh >= 0) ? MVK[(q*32 + t)*10 + hh] : 0u;
        if (v > best){ best = v; bq = q; }
      }
      cand[ob + s] = (u16)(best & 2047u);
      #pragma unroll
      for (int q = 0; q < 16; ++q) head[q] -= (q == bq) ? 1 : 0;
    }
  }
}

// ---------------- K1b: f64 refine, register-only, shuffle-rank top-11 ----------------
__global__ __launch_bounds__(256) void refine_kernel(const float* __restrict__ xT,
                                                     const u16* __restrict__ cand,
                                                     const double* __restrict__ xxd,
                                                     int* __restrict__ idxout){
  const int wv = threadIdx.x >> 6, ln = threadIdx.x & 63;
  const int g = blockIdx.x * 4 + wv;               // 0..16383
  const int b = g >> 11, n = g & 2047;
  const int c = ln >> 2, part = ln & 3;
  const int m = (int)cand[(size_t)g*16 + c] & 2047;
  const float4* pn = (const float4*)(xT + ((size_t)b*N_ + n)*192 + part*48);
  const float4* pm = (const float4*)(xT + ((size_t)b*N_ + m)*192 + part*48);
  double s = 0.0;
  #pragma unroll
  for (int j = 0; j < 12; ++j){                    // d ascending: same f64 order as before
    float4 a = pn[j], bb = pm[j];
    s = fma((double)a.x, (double)bb.x, s);
    s = fma((double)a.y, (double)bb.y, s);
    s = fma((double)a.z, (double)bb.z, s);
    s = fma((double)a.w, (double)bb.w, s);
  }
  s += __shfl_down(s, 2, 64);
  s += __shfl_down(s, 1, 64);                      // part==0 lanes hold full dot
  double v = 2.0*s - xxd[b*N_ + n] - xxd[b*N_ + m];
  int rank = 0;
  #pragma unroll
  for (int q = 0; q < 16; ++q){
    double vq = __shfl(v, q*4, 64);
    int    mq = __shfl(m, q*4, 64);
    bool beat = (vq > v) || ((vq == v) && (mq < m));
    rank += beat ? 1 : 0;
  }
  if (part == 0 && rank < KNb)
    idxout[(size_t)g*KNb + rank] = m;
}

// ---------------- K2: P0/D0 from xT, 16-pt tiles, (256,2) ----------------
// Empirical launch_bounds map on this toolchain: (256,4) -> 64-VGPR cap -> forced
// spill (R3: 400MB scratch; R5 role-split: same). (256,2) -> 128-VGPR cap, which
// R2 PROVED holds this exact body with zero scratch (unified AGPR file absorbs
// overflow). So: R2's verified body + attribute, 16-pt tiles, grid (8,128) =
// 4 blocks/CU x 4 waves = 16 waves/CU. Same fma order -> bitwise-identical output.
__global__ __launch_bounds__(256, 2) void project_kernel(const float* __restrict__ xT,
                                                         const float* __restrict__ Wf,
                                                         const float* __restrict__ Wd,
                                                         h4* __restrict__ P0h,
                                                         h4* __restrict__ D0h){
  __shared__ float A[16 * 192];                    // 12 KB, [m][e]
  const int b = blockIdx.x, m0 = blockIdx.y * 16, t = threadIdx.x;
  const int c = t & 63, mg = t >> 6;               // 4 groups of 4 points

  float wf[64], wd[64];
  #pragma unroll
  for (int q = 0; q < 16; ++q){
    float4 uf = *(const float4*)(Wf + c*64 + q*4);
    wf[q*4+0]=uf.x; wf[q*4+1]=uf.y; wf[q*4+2]=uf.z; wf[q*4+3]=uf.w;
    float4 ud = *(const float4*)(Wd + c*64 + q*4);
    wd[q*4+0]=ud.x; wd[q*4+1]=ud.y; wd[q*4+2]=ud.z; wd[q*4+3]=ud.w;
  }
  {
    const float4* src = (const float4*)(xT + ((size_t)b*N_ + m0)*192);
    float4* dst = (float4*)A;
    #pragma unroll
    for (int j = 0; j < 3; ++j) dst[t + 256*j] = src[t + 256*j];
  }
  __syncthreads();

  for (int mi = 0; mi < 4; ++mi){
    int m = mg*4 + mi;
    const float4* row = (const float4*)(A + m*192);
    float p[3] = {0.f,0.f,0.f}, qv[3] = {0.f,0.f,0.f};
    #pragma unroll
    for (int v4 = 0; v4 < 48; ++v4){
      float4 f = row[v4];
      const int e = v4*4;
      p [(e+0)%3] = fmaf(wf[(e+0)/3], f.x, p [(e+0)%3]);
      qv[(e+0)%3] = fmaf(wd[(e+0)/3], f.x, qv[(e+0)%3]);
      p [(e+1)%3] = fmaf(wf[(e+1)/3], f.y, p [(e+1)%3]);
      qv[(e+1)%3] = fmaf(wd[(e+1)/3], f.y, qv[(e+1)%3]);
      p [(e+2)%3] = fmaf(wf[(e+2)/3], f.z, p [(e+2)%3]);
      qv[(e+2)%3] = fmaf(wd[(e+2)/3], f.z, qv[(e+2)%3]);
      p [(e+3)%3] = fmaf(wf[(e+3)/3], f.w, p [(e+3)%3]);
      qv[(e+3)%3] = fmaf(wd[(e+3)/3], f.w, qv[(e+3)%3]);
    }
    float nrm = sqrtf(p[0]*p[0] + p[1]*p[1] + p[2]*p[2]);
    float dsq = qv[0]*qv[0] + qv[1]*qv[1] + qv[2]*qv[2];
    size_t base = ((size_t)b*N_ + m0 + m)*64 + c;
    h4 vp; vp.x = (f16)p[0];  vp.y = (f16)p[1];  vp.z = (f16)p[2];  vp.w = (f16)nrm;
    h4 vd; vd.x = (f16)qv[0]; vd.y = (f16)qv[1]; vd.z = (f16)qv[2]; vd.w = (f16)dsq;
    P0h[base] = vp;
    D0h[base] = vd;
  }
}

// ---------------- K3a: neighbor occurrence counts ----------------
__global__ __launch_bounds__(256) void count_kernel(const int* __restrict__ idxin, int* __restrict__ cnt){
  int i = blockIdx.x*256 + threadIdx.x;
  if (i < B_*N_*KNb){
    int b = i / (N_*KNb);
    atomicAdd(&cnt[b*N_ + (idxin[i] & 2047)], 1);
  }
}

// ---------------- K3b: per-channel weighted sum / sumsq of norms ----------------
__global__ __launch_bounds__(256) void stats_kernel(const h4* __restrict__ P0h,
                                                    const int* __restrict__ cnt,
                                                    float* __restrict__ gs){
  const int b = blockIdx.x >> 3;
  const int chunk = blockIdx.x & 7;
  const int w = threadIdx.x >> 6, c = threadIdx.x & 63;
  float s = 0.f, s2 = 0.f;
  const int mbase = chunk*256 + w*64;
  for (int i = 0; i < 64; ++i){
    int m = mbase + i;
    float wt = (float)cnt[b*N_ + m];
    float nv = (float)P0h[((size_t)b*N_ + m)*64 + c].w;
    s  = fmaf(wt, nv, s);
    s2 = fmaf(wt*nv, nv, s2);
  }
  __shared__ float red[8][64];
  red[w][c] = s; red[4+w][c] = s2;
  __syncthreads();
  if (w == 0) atomicAdd(&gs[c],    red[0][c]+red[1][c]+red[2][c]+red[3][c]);
  if (w == 1) atomicAdd(&gs[64+c], red[4][c]+red[5][c]+red[6][c]+red[7][c]);
}

// ---------------- K4: gather + BN + nonlinearity + mean over K ----------------
__global__ __launch_bounds__(512) void out_kernel(const h4* __restrict__ P0h, const h4* __restrict__ D0h,
                                                  const int* __restrict__ idxin, const float* __restrict__ gs,
                                                  const float* __restrict__ gamma, const float* __restrict__ beta,
                                                  float* __restrict__ outp){
  __shared__ float res[64 * 193];                  // 49,408 B
  const int b  = blockIdx.x;
  const int n0 = blockIdx.y * 64;
  const int t = threadIdx.x, w = t >> 6, c = t & 63;
  const float Ninv = 1.f / (float)(B_*N_*KNb);
  float mean = gs[c] * Ninv;
  float var  = gs[64+c] * Ninv - mean*mean;
  float istd = rsqrtf(var + 1e-5f);
  float sa = istd * gamma[c];
  float be = beta[c];
  const float kinv = 1.f/11.f;
  for (int i = 0; i < 8; ++i){
    int n = n0 + w*8 + i;
    const int* ip = idxin + ((size_t)b*N_ + n)*KNb;
    float a0=0, a1=0, a2=0;
    #pragma unroll
    for (int k = 0; k < KNb; ++k){
      int m = ip[k] & 2047;
      size_t base = ((size_t)b*N_ + m)*64 + c;
      h4 P  = P0h[base];
      h4 Dv = D0h[base];
      float pw = (float)P.w;
      float nb = (pw - mean)*sa + be;
      float sc = nb / pw;
      float p0 = (float)P.x*sc, p1 = (float)P.y*sc, p2 = (float)P.z*sc;
      float d0 = (float)Dv.x, d1 = (float)Dv.y, d2 = (float)Dv.z;
      float dot = p0*d0 + p1*d1 + p2*d2;
      float f = (dot >= 0.f) ? 0.f : dot / ((float)Dv.w + 1e-6f);
      a0 += p0 - f*d0; a1 += p1 - f*d1; a2 += p2 - f*d2;
    }
    int row = w*8 + i;
    res[row*193 + 3*c + 0] = a0*kinv;
    res[row*193 + 3*c + 1] = a1*kinv;
    res[row*193 + 3*c + 2] = a2*kinv;
  }
  __syncthreads();
  #pragma unroll
  for (int j = 0; j < 6; ++j){
    int p = t + 512*j;
    int cdim = p >> 4, nq = p & 15;
    float4 v = { res[(nq*4 + 0)*193 + cdim], res[(nq*4 + 1)*193 + cdim],
                 res[(nq*4 + 2)*193 + cdim], res[(nq*4 + 3)*193 + cdim] };
    *(float4*)(outp + ((size_t)b*192 + cdim)*N_ + n0 + nq*4) = v;
  }
}

extern "C" void kernel_launch(void* const* d_in, const int* in_sizes, int n_in,
                              void* d_out, int out_size, void* d_ws, size_t ws_size,
                              hipStream_t stream){
  const float* x     = (const float*)d_in[0];
  const float* Wf    = (const float*)d_in[1];
  const float* Wd    = (const float*)d_in[2];
  const float* gamma = (const float*)d_in[3];
  const float* beta  = (const float*)d_in[4];
  float* outp = (float*)d_out;

  char* ws = (char*)d_ws;
  int*    idx  = (int*)   (ws);                 // 720,896
  int*    cnt  = (int*)   (ws + 720896);        // 65,536
  float*  gs   = (float*) (ws + 786432);        // 512
  h4*     P0h  = (h4*)    (ws + 1048576);       // 8,388,608
  h4*     D0h  = (h4*)    (ws + 9437184);       // 8,388,608 (ends 17,825,792)
  short*  Xs   = (short*) (ws + 1048576);       //   alias (6,291,456), consumed pre-project
  double* xxd  = (double*)(ws + 13631488);      //   alias (lives in D0h region pre-project)
  u16*    cand = (u16*)   (ws + 13762560);      //   alias
  float*  xT   = (float*) (ws + 17825792);      // 12,582,912 (ends 30,408,704)

  hipMemsetAsync(cnt, 0, 66048, stream);        // zero cnt + gs (contiguous)
  split_kernel  <<<dim3(32, 8),  256, 0, stream>>>(x, Xs, xT, xxd);
  knn_kernel    <<<dim3(8, 64),  512, 0, stream>>>(Xs, xxd, cand);
  refine_kernel <<<4096,         256, 0, stream>>>(xT, cand, xxd, idx);
  project_kernel<<<dim3(8, 128), 256, 0, stream>>>(xT, Wf, Wd, P0h, D0h);
  count_kernel  <<<704,          256, 0, stream>>>(idx, cnt);
  stats_kernel  <<<64,           256, 0, stream>>>(P0h, cnt, gs);
  out_kernel    <<<dim3(8, 32),  512, 0, stream>>>(P0h, D0h, idx, gs, gamma, beta, outp);
}

// Round 7
// 278.520 us; speedup vs baseline: 1.4096x; 1.0606x over previous
//
#include <hip/hip_runtime.h>
#include <stdint.h>

#define B_   8
#define D_   192      // Cin*3
#define N_   2048
#define KNb  11       // k+1

using u32 = uint32_t;
using u16 = unsigned short;
typedef _Float16 f16;
struct alignas(8) h4 { f16 x, y, z, w; };

typedef __attribute__((ext_vector_type(8)))  short short8;
typedef __attribute__((ext_vector_type(16))) float f32x16;

__device__ __forceinline__ float bf2f(u16 h){ union{u32 i; float f;} x; x.i = ((u32)h) << 16; return x.f; }
__device__ __forceinline__ u16 f2bf(float f){
  union{float f; u32 i;} x; x.f = f;
  u32 r = (x.i + 0x7fffu + ((x.i >> 16) & 1u)) >> 16;
  return (u16)r;
}
__device__ __forceinline__ u32 umax32(u32 a, u32 b){ return a > b ? a : b; }
__device__ __forceinline__ u32 umin32(u32 a, u32 b){ return a < b ? a : b; }

// ---------------- K0: bf16 fragment-page emit + fp32 transpose + f64 xx ----------------
// Xs layout: page P = (b*64 + tile)*12 + chunk, data[P][lane=lh*32+l31][8 shorts]
//   = bf16 of x[row = tile*32 + l31][d = chunk*16 + lh*8 + 0..8)].
// This is exactly the mfma_32x32x16_bf16 A/B fragment order -> knn loads are 1KB contiguous.
__global__ __launch_bounds__(256) void split_kernel(const float* __restrict__ x,
                                                    short* __restrict__ Xs,
                                                    float* __restrict__ xT,
                                                    double* __restrict__ xxd){
  __shared__ float A[D_ * 64];                       // 48 KB, [d][m]
  const int b = blockIdx.y, m0 = blockIdx.x * 64, t = threadIdx.x;
  const size_t xb = (size_t)b * D_ * N_;
  #pragma unroll
  for (int q = 0; q < 48; ++q){
    int p = t + 256*q;
    int d = p >> 6, i = p & 63;
    A[d*64 + i] = x[xb + (size_t)d*N_ + m0 + i];
  }
  __syncthreads();

  // bf16 fragment pages (hi only): 24 pages/block, wave-contiguous 1KB stores
  {
    const int l = t & 63, wv = t >> 6;
    const int lh = l >> 5, l31 = l & 31;
    #pragma unroll
    for (int j = 0; j < 6; ++j){
      int p  = j*4 + wv;                 // page within block 0..23
      int tt = p / 12, c = p % 12;       // tile, chunk
      int dbase = c*16 + lh*8;
      int row = tt*32 + l31;
      union{ u16 s[8]; int4 v; } u;
      #pragma unroll
      for (int q = 0; q < 8; ++q) u.s[q] = f2bf(A[(dbase + q)*64 + row]);
      size_t P = ((size_t)b*64 + blockIdx.x*2 + tt)*12 + c;
      *(int4*)(Xs + P*512 + l*8) = u.v;
    }
  }
  {
    const int m = t & 63, seg = t >> 6;
    float* trow = xT + ((size_t)b*N_ + m0 + m) * 192 + seg*48;
    #pragma unroll
    for (int j = 0; j < 12; ++j){
      float4 v = { A[(seg*48 + 4*j + 0)*64 + m], A[(seg*48 + 4*j + 1)*64 + m],
                   A[(seg*48 + 4*j + 2)*64 + m], A[(seg*48 + 4*j + 3)*64 + m] };
      *(float4*)(trow + 4*j) = v;
    }
  }
  if (t < 64){
    double s = 0.0;
    #pragma unroll 4
    for (int d = 0; d < D_; ++d){ double v = (double)A[d*64 + t]; s = fma(v, v, s); }
    xxd[b*N_ + m0 + t] = s;
  }
}

// ---------------- K1: MFMA kNN, 32-row stripes, fragment-page streaming ----------------
#define KLA   0         // 12,288 : A pages (12 x 1024)
#define KLCT  12288     // float[32*260] = 33,280 (aliased by merge keys)
#define KLXXS 45568     // 256 f32
#define KLXXN 46592     // 32 f32
#define KLSZ  46720
__global__ __launch_bounds__(512, 6) void knn_kernel(const short* __restrict__ Xs,
                                                     const double* __restrict__ xxd,
                                                     u16* __restrict__ cand){
  __shared__ __align__(16) char smem[KLSZ];
  float* CT  = (float*)(smem + KLCT);
  float* XXS = (float*)(smem + KLXXS);
  float* XXN = (float*)(smem + KLXXN);

  const int b = blockIdx.x, n0 = blockIdx.y * 32;
  const int t = threadIdx.x, lane = t & 63, w = t >> 6;
  const int l31 = lane & 31, lh = lane >> 5;

  // stage A (12 pages = query tile n0>>5), contiguous loads + linear LDS
  {
    const short* Ap = Xs + (((size_t)b*64 + (n0 >> 5)) * 12) * 512;
    #pragma unroll
    for (int j = 0; j < 2; ++j){
      int p = t + 512*j;                  // frag id 0..767
      if (j == 0 || t < 256){
        int4 v = *(const int4*)(Ap + (size_t)p*8);
        *(int4*)(smem + KLA + p*16) = v;
      }
    }
  }
  if (t < 32) XXN[t] = (float)xxd[b*N_ + n0 + t];

  u32 key[10];                                   // sorted ascending packed keys
  #pragma unroll
  for (int j = 0; j < 10; ++j) key[j] = 0u;

  for (int st = 0; st < 8; ++st){
    const int m0 = st * 256;
    __syncthreads();                             // prev selection done; A staged (st==0)
    if (t < 256) XXS[t] = (float)xxd[b*N_ + m0 + t];

    // wave w consumes neighbor tile (m0>>5)+w; pages are contiguous per wave
    const short* Bp = Xs + (((size_t)b*64 + (m0 >> 5) + w) * 12) * 512 + lane*8;
    short8 b0 = *(const short8*)(Bp + 0*512);
    short8 b1 = *(const short8*)(Bp + 1*512);
    short8 c0 = *(const short8*)(Bp + 2*512);
    short8 c1 = *(const short8*)(Bp + 3*512);
    short8 d0 = *(const short8*)(Bp + 4*512);
    short8 d1 = *(const short8*)(Bp + 5*512);
    f32x16 acc = (f32x16)0.0f;
    #pragma unroll
    for (int kc = 0; kc < 6; ++kc){
      short8 a0 = *(const short8*)(smem + KLA + (kc*2+0)*1024 + lane*16);
      short8 a1 = *(const short8*)(smem + KLA + (kc*2+1)*1024 + lane*16);
      acc = __builtin_amdgcn_mfma_f32_32x32x16_bf16(a0, b0, acc, 0, 0, 0);
      acc = __builtin_amdgcn_mfma_f32_32x32x16_bf16(a1, b1, acc, 0, 0, 0);
      b0 = c0; b1 = c1; c0 = d0; c1 = d1;
      if (kc < 3){
        d0 = *(const short8*)(Bp + (kc*2+6)*512);
        d1 = *(const short8*)(Bp + (kc*2+7)*512);
      }
    }

    #pragma unroll
    for (int reg = 0; reg < 16; ++reg){
      int r = (reg & 3) + 8*(reg >> 2) + 4*lh;
      CT[r*260 + w*32 + l31] = acc[reg];
    }
    __syncthreads();

    {
      const int r = t & 31, sub = t >> 5;
      const float xn = XXN[r];
      const float* ctp = CT + r*260 + sub*16;
      const float* xsp = XXS + sub*16;
      const int mb = m0 + sub*16;
      #pragma unroll
      for (int q = 0; q < 4; ++q){
        float4 cv = *(const float4*)(ctp + 4*q);
        float4 xv = *(const float4*)(xsp + 4*q);
        float vs[4]  = {cv.x, cv.y, cv.z, cv.w};
        float xs4[4] = {xv.x, xv.y, xv.z, xv.w};
        #pragma unroll
        for (int j = 0; j < 4; ++j){
          float v = fmaf(2.f, vs[j], -(xs4[j] + xn));
          u32 bbits = __float_as_uint(v);
          u32 kk = ((bbits ^ (u32)(((int)bbits >> 31) | 0x80000000)) & 0xFFFFF800u)
                   | (u32)(mb + 4*q + j);
          #pragma unroll
          for (int s = 0; s < 9; ++s) key[s] = umin32(key[s+1], umax32(kk, key[s]));
          key[9] = umax32(kk, key[9]);
        }
      }
    }
  }

  // merge 16 sorted lists x 10 per row -> top-16 window (static indexing only)
  __syncthreads();
  u32* MVK = (u32*)(smem + KLCT);                 // 16*32*10*4 = 20,480
  {
    const int r = t & 31, sub = t >> 5;
    #pragma unroll
    for (int j = 0; j < 10; ++j) MVK[(sub*32 + r)*10 + j] = key[j];
  }
  __syncthreads();
  if (t < 32){
    int head[16];
    #pragma unroll
    for (int q = 0; q < 16; ++q) head[q] = 9;
    const size_t ob = ((size_t)b*N_ + n0 + t) * 16;
    for (int s = 0; s < 16; ++s){
      u32 best = 0u; int bq = 0;
      #pragma unroll
      for (int q = 0; q < 16; ++q){
        int hh = head[q];
        u32 v = (hh >= 0) ? MVK[(q*32 + t)*10 + hh] : 0u;
        if (v > best){ best = v; bq = q; }
      }
      cand[ob + s] = (u16)(best & 2047u);
      #pragma unroll
      for (int q = 0; q < 16; ++q) head[q] -= (q == bq) ? 1 : 0;
    }
  }
}

// ---------------- K1b: f64 refine, register-only, shuffle-rank top-11 ----------------
__global__ __launch_bounds__(256) void refine_kernel(const float* __restrict__ xT,
                                                     const u16* __restrict__ cand,
                                                     const double* __restrict__ xxd,
                                                     int* __restrict__ idxout){
  const int wv = threadIdx.x >> 6, ln = threadIdx.x & 63;
  const int g = blockIdx.x * 4 + wv;               // 0..16383
  const int b = g >> 11, n = g & 2047;
  const int c = ln >> 2, part = ln & 3;
  const int m = (int)cand[(size_t)g*16 + c] & 2047;
  const float4* pn = (const float4*)(xT + ((size_t)b*N_ + n)*192 + part*48);
  const float4* pm = (const float4*)(xT + ((size_t)b*N_ + m)*192 + part*48);
  double s = 0.0;
  #pragma unroll
  for (int j = 0; j < 12; ++j){                    // d ascending: same f64 order as before
    float4 a = pn[j], bb = pm[j];
    s = fma((double)a.x, (double)bb.x, s);
    s = fma((double)a.y, (double)bb.y, s);
    s = fma((double)a.z, (double)bb.z, s);
    s = fma((double)a.w, (double)bb.w, s);
  }
  s += __shfl_down(s, 2, 64);
  s += __shfl_down(s, 1, 64);                      // part==0 lanes hold full dot
  double v = 2.0*s - xxd[b*N_ + n] - xxd[b*N_ + m];
  int rank = 0;
  #pragma unroll
  for (int q = 0; q < 16; ++q){
    double vq = __shfl(v, q*4, 64);
    int    mq = __shfl(m, q*4, 64);
    bool beat = (vq > v) || ((vq == v) && (mq < m));
    rank += beat ? 1 : 0;
  }
  if (part == 0 && rank < KNb)
    idxout[(size_t)g*KNb + rank] = m;
}

// ---------------- K2: P0/D0 from xT, 16-pt tiles, natural VGPR ----------------
// Spill ledger: (256,4)->64-cap: 400MB scratch (R3/R5). (256,2)->128-cap: STILL
// ~230B/thread scratch (R2 and R6 both show it in WRITE_SIZE). Natural footprint
// is ~150 VGPR (128 weight floats + state), so ANY cap <=128 spills. Fix: no
// min-waves clause -> allocator takes ~150-170 VGPR, zero scratch, 3 waves/SIMD
// x 3 blocks/CU = 12 waves/CU. Same fma order -> bitwise-identical output.
__global__ __launch_bounds__(256) void project_kernel(const float* __restrict__ xT,
                                                      const float* __restrict__ Wf,
                                                      const float* __restrict__ Wd,
                                                      h4* __restrict__ P0h,
                                                      h4* __restrict__ D0h){
  __shared__ float A[16 * 192];                    // 12 KB, [m][e]
  const int b = blockIdx.x, m0 = blockIdx.y * 16, t = threadIdx.x;
  const int c = t & 63, mg = t >> 6;               // 4 groups of 4 points

  float wf[64], wd[64];
  #pragma unroll
  for (int q = 0; q < 16; ++q){
    float4 uf = *(const float4*)(Wf + c*64 + q*4);
    wf[q*4+0]=uf.x; wf[q*4+1]=uf.y; wf[q*4+2]=uf.z; wf[q*4+3]=uf.w;
    float4 ud = *(const float4*)(Wd + c*64 + q*4);
    wd[q*4+0]=ud.x; wd[q*4+1]=ud.y; wd[q*4+2]=ud.z; wd[q*4+3]=ud.w;
  }
  {
    const float4* src = (const float4*)(xT + ((size_t)b*N_ + m0)*192);
    float4* dst = (float4*)A;
    #pragma unroll
    for (int j = 0; j < 3; ++j) dst[t + 256*j] = src[t + 256*j];
  }
  __syncthreads();

  for (int mi = 0; mi < 4; ++mi){
    int m = mg*4 + mi;
    const float4* row = (const float4*)(A + m*192);
    float p[3] = {0.f,0.f,0.f}, qv[3] = {0.f,0.f,0.f};
    #pragma unroll
    for (int v4 = 0; v4 < 48; ++v4){
      float4 f = row[v4];
      const int e = v4*4;
      p [(e+0)%3] = fmaf(wf[(e+0)/3], f.x, p [(e+0)%3]);
      qv[(e+0)%3] = fmaf(wd[(e+0)/3], f.x, qv[(e+0)%3]);
      p [(e+1)%3] = fmaf(wf[(e+1)/3], f.y, p [(e+1)%3]);
      qv[(e+1)%3] = fmaf(wd[(e+1)/3], f.y, qv[(e+1)%3]);
      p [(e+2)%3] = fmaf(wf[(e+2)/3], f.z, p [(e+2)%3]);
      qv[(e+2)%3] = fmaf(wd[(e+2)/3], f.z, qv[(e+2)%3]);
      p [(e+3)%3] = fmaf(wf[(e+3)/3], f.w, p [(e+3)%3]);
      qv[(e+3)%3] = fmaf(wd[(e+3)/3], f.w, qv[(e+3)%3]);
    }
    float nrm = sqrtf(p[0]*p[0] + p[1]*p[1] + p[2]*p[2]);
    float dsq = qv[0]*qv[0] + qv[1]*qv[1] + qv[2]*qv[2];
    size_t base = ((size_t)b*N_ + m0 + m)*64 + c;
    h4 vp; vp.x = (f16)p[0];  vp.y = (f16)p[1];  vp.z = (f16)p[2];  vp.w = (f16)nrm;
    h4 vd; vd.x = (f16)qv[0]; vd.y = (f16)qv[1]; vd.z = (f16)qv[2]; vd.w = (f16)dsq;
    P0h[base] = vp;
    D0h[base] = vd;
  }
}

// ---------------- K3a: neighbor occurrence counts ----------------
__global__ __launch_bounds__(256) void count_kernel(const int* __restrict__ idxin, int* __restrict__ cnt){
  int i = blockIdx.x*256 + threadIdx.x;
  if (i < B_*N_*KNb){
    int b = i / (N_*KNb);
    atomicAdd(&cnt[b*N_ + (idxin[i] & 2047)], 1);
  }
}

// ---------------- K3b: per-channel weighted sum / sumsq of norms ----------------
__global__ __launch_bounds__(256) void stats_kernel(const h4* __restrict__ P0h,
                                                    const int* __restrict__ cnt,
                                                    float* __restrict__ gs){
  const int b = blockIdx.x >> 3;
  const int chunk = blockIdx.x & 7;
  const int w = threadIdx.x >> 6, c = threadIdx.x & 63;
  float s = 0.f, s2 = 0.f;
  const int mbase = chunk*256 + w*64;
  for (int i = 0; i < 64; ++i){
    int m = mbase + i;
    float wt = (float)cnt[b*N_ + m];
    float nv = (float)P0h[((size_t)b*N_ + m)*64 + c].w;
    s  = fmaf(wt, nv, s);
    s2 = fmaf(wt*nv, nv, s2);
  }
  __shared__ float red[8][64];
  red[w][c] = s; red[4+w][c] = s2;
  __syncthreads();
  if (w == 0) atomicAdd(&gs[c],    red[0][c]+red[1][c]+red[2][c]+red[3][c]);
  if (w == 1) atomicAdd(&gs[64+c], red[4][c]+red[5][c]+red[6][c]+red[7][c]);
}

// ---------------- K4: gather + BN + nonlinearity + mean over K ----------------
__global__ __launch_bounds__(512) void out_kernel(const h4* __restrict__ P0h, const h4* __restrict__ D0h,
                                                  const int* __restrict__ idxin, const float* __restrict__ gs,
                                                  const float* __restrict__ gamma, const float* __restrict__ beta,
                                                  float* __restrict__ outp){
  __shared__ float res[64 * 193];                  // 49,408 B
  const int b  = blockIdx.x;
  const int n0 = blockIdx.y * 64;
  const int t = threadIdx.x, w = t >> 6, c = t & 63;
  const float Ninv = 1.f / (float)(B_*N_*KNb);
  float mean = gs[c] * Ninv;
  float var  = gs[64+c] * Ninv - mean*mean;
  float istd = rsqrtf(var + 1e-5f);
  float sa = istd * gamma[c];
  float be = beta[c];
  const float kinv = 1.f/11.f;
  for (int i = 0; i < 8; ++i){
    int n = n0 + w*8 + i;
    const int* ip = idxin + ((size_t)b*N_ + n)*KNb;
    float a0=0, a1=0, a2=0;
    #pragma unroll
    for (int k = 0; k < KNb; ++k){
      int m = ip[k] & 2047;
      size_t base = ((size_t)b*N_ + m)*64 + c;
      h4 P  = P0h[base];
      h4 Dv = D0h[base];
      float pw = (float)P.w;
      float nb = (pw - mean)*sa + be;
      float sc = nb / pw;
      float p0 = (float)P.x*sc, p1 = (float)P.y*sc, p2 = (float)P.z*sc;
      float d0 = (float)Dv.x, d1 = (float)Dv.y, d2 = (float)Dv.z;
      float dot = p0*d0 + p1*d1 + p2*d2;
      float f = (dot >= 0.f) ? 0.f : dot / ((float)Dv.w + 1e-6f);
      a0 += p0 - f*d0; a1 += p1 - f*d1; a2 += p2 - f*d2;
    }
    int row = w*8 + i;
    res[row*193 + 3*c + 0] = a0*kinv;
    res[row*193 + 3*c + 1] = a1*kinv;
    res[row*193 + 3*c + 2] = a2*kinv;
  }
  __syncthreads();
  #pragma unroll
  for (int j = 0; j < 6; ++j){
    int p = t + 512*j;
    int cdim = p >> 4, nq = p & 15;
    float4 v = { res[(nq*4 + 0)*193 + cdim], res[(nq*4 + 1)*193 + cdim],
                 res[(nq*4 + 2)*193 + cdim], res[(nq*4 + 3)*193 + cdim] };
    *(float4*)(outp + ((size_t)b*192 + cdim)*N_ + n0 + nq*4) = v;
  }
}

extern "C" void kernel_launch(void* const* d_in, const int* in_sizes, int n_in,
                              void* d_out, int out_size, void* d_ws, size_t ws_size,
                              hipStream_t stream){
  const float* x     = (const float*)d_in[0];
  const float* Wf    = (const float*)d_in[1];
  const float* Wd    = (const float*)d_in[2];
  const float* gamma = (const float*)d_in[3];
  const float* beta  = (const float*)d_in[4];
  float* outp = (float*)d_out;

  char* ws = (char*)d_ws;
  int*    idx  = (int*)   (ws);                 // 720,896
  int*    cnt  = (int*)   (ws + 720896);        // 65,536
  float*  gs   = (float*) (ws + 786432);        // 512
  h4*     P0h  = (h4*)    (ws + 1048576);       // 8,388,608
  h4*     D0h  = (h4*)    (ws + 9437184);       // 8,388,608 (ends 17,825,792)
  short*  Xs   = (short*) (ws + 1048576);       //   alias (6,291,456), consumed pre-project
  double* xxd  = (double*)(ws + 13631488);      //   alias (lives in D0h region pre-project)
  u16*    cand = (u16*)   (ws + 13762560);      //   alias
  float*  xT   = (float*) (ws + 17825792);      // 12,582,912 (ends 30,408,704)

  hipMemsetAsync(cnt, 0, 66048, stream);        // zero cnt + gs (contiguous)
  split_kernel  <<<dim3(32, 8),  256, 0, stream>>>(x, Xs, xT, xxd);
  knn_kernel    <<<dim3(8, 64),  512, 0, stream>>>(Xs, xxd, cand);
  refine_kernel <<<4096,         256, 0, stream>>>(xT, cand, xxd, idx);
  project_kernel<<<dim3(8, 128), 256, 0, stream>>>(xT, Wf, Wd, P0h, D0h);
  count_kernel  <<<704,          256, 0, stream>>>(idx, cnt);
  stats_kernel  <<<64,           256, 0, stream>>>(P0h, cnt, gs);
  out_kernel    <<<dim3(8, 32),  512, 0, stream>>>(P0h, D0h, idx, gs, gamma, beta, outp);
}

// Round 8
// 257.901 us; speedup vs baseline: 1.5223x; 1.0799x over previous
//
#include <hip/hip_runtime.h>
#include <stdint.h>

#define B_   8
#define D_   192      // Cin*3
#define N_   2048
#define KNb  11       // k+1

using u32 = uint32_t;
using u16 = unsigned short;
typedef _Float16 f16;
struct alignas(8) h4 { f16 x, y, z, w; };

typedef __attribute__((ext_vector_type(8)))  short short8;
typedef __attribute__((ext_vector_type(16))) float f32x16;

__device__ __forceinline__ float bf2f(u16 h){ union{u32 i; float f;} x; x.i = ((u32)h) << 16; return x.f; }
__device__ __forceinline__ u16 f2bf(float f){
  union{float f; u32 i;} x; x.f = f;
  u32 r = (x.i + 0x7fffu + ((x.i >> 16) & 1u)) >> 16;
  return (u16)r;
}
__device__ __forceinline__ u32 umax32(u32 a, u32 b){ return a > b ? a : b; }
__device__ __forceinline__ u32 umin32(u32 a, u32 b){ return a < b ? a : b; }

// ---------------- K0: bf16 fragment-page emit + fp32 transpose + f64 xx ----------------
// Xs layout: page P = (b*64 + tile)*12 + chunk, data[P][lane=lh*32+l31][8 shorts]
//   = bf16 of x[row = tile*32 + l31][d = chunk*16 + lh*8 + 0..8)].
// This is exactly the mfma_32x32x16_bf16 A/B fragment order -> knn loads are 1KB contiguous.
__global__ __launch_bounds__(256) void split_kernel(const float* __restrict__ x,
                                                    short* __restrict__ Xs,
                                                    float* __restrict__ xT,
                                                    double* __restrict__ xxd){
  __shared__ float A[D_ * 64];                       // 48 KB, [d][m]
  const int b = blockIdx.y, m0 = blockIdx.x * 64, t = threadIdx.x;
  const size_t xb = (size_t)b * D_ * N_;
  #pragma unroll
  for (int q = 0; q < 48; ++q){
    int p = t + 256*q;
    int d = p >> 6, i = p & 63;
    A[d*64 + i] = x[xb + (size_t)d*N_ + m0 + i];
  }
  __syncthreads();

  // bf16 fragment pages (hi only): 24 pages/block, wave-contiguous 1KB stores
  {
    const int l = t & 63, wv = t >> 6;
    const int lh = l >> 5, l31 = l & 31;
    #pragma unroll
    for (int j = 0; j < 6; ++j){
      int p  = j*4 + wv;                 // page within block 0..23
      int tt = p / 12, c = p % 12;       // tile, chunk
      int dbase = c*16 + lh*8;
      int row = tt*32 + l31;
      union{ u16 s[8]; int4 v; } u;
      #pragma unroll
      for (int q = 0; q < 8; ++q) u.s[q] = f2bf(A[(dbase + q)*64 + row]);
      size_t P = ((size_t)b*64 + blockIdx.x*2 + tt)*12 + c;
      *(int4*)(Xs + P*512 + l*8) = u.v;
    }
  }
  {
    const int m = t & 63, seg = t >> 6;
    float* trow = xT + ((size_t)b*N_ + m0 + m) * 192 + seg*48;
    #pragma unroll
    for (int j = 0; j < 12; ++j){
      float4 v = { A[(seg*48 + 4*j + 0)*64 + m], A[(seg*48 + 4*j + 1)*64 + m],
                   A[(seg*48 + 4*j + 2)*64 + m], A[(seg*48 + 4*j + 3)*64 + m] };
      *(float4*)(trow + 4*j) = v;
    }
  }
  if (t < 64){
    double s = 0.0;
    #pragma unroll 4
    for (int d = 0; d < D_; ++d){ double v = (double)A[d*64 + t]; s = fma(v, v, s); }
    xxd[b*N_ + m0 + t] = s;
  }
}

// ---------------- K1: MFMA kNN, 32-row stripes, fragment-page streaming ----------------
#define KLA   0         // 12,288 : A pages (12 x 1024)
#define KLCT  12288     // float[32*260] = 33,280 (aliased by merge keys)
#define KLXXS 45568     // 256 f32
#define KLXXN 46592     // 32 f32
#define KLSZ  46720
__global__ __launch_bounds__(512, 6) void knn_kernel(const short* __restrict__ Xs,
                                                     const double* __restrict__ xxd,
                                                     u16* __restrict__ cand){
  __shared__ __align__(16) char smem[KLSZ];
  float* CT  = (float*)(smem + KLCT);
  float* XXS = (float*)(smem + KLXXS);
  float* XXN = (float*)(smem + KLXXN);

  const int b = blockIdx.x, n0 = blockIdx.y * 32;
  const int t = threadIdx.x, lane = t & 63, w = t >> 6;
  const int l31 = lane & 31, lh = lane >> 5;

  // stage A (12 pages = query tile n0>>5), contiguous loads + linear LDS
  {
    const short* Ap = Xs + (((size_t)b*64 + (n0 >> 5)) * 12) * 512;
    #pragma unroll
    for (int j = 0; j < 2; ++j){
      int p = t + 512*j;                  // frag id 0..767
      if (j == 0 || t < 256){
        int4 v = *(const int4*)(Ap + (size_t)p*8);
        *(int4*)(smem + KLA + p*16) = v;
      }
    }
  }
  if (t < 32) XXN[t] = (float)xxd[b*N_ + n0 + t];

  u32 key[10];                                   // sorted ascending packed keys
  #pragma unroll
  for (int j = 0; j < 10; ++j) key[j] = 0u;

  for (int st = 0; st < 8; ++st){
    const int m0 = st * 256;
    __syncthreads();                             // prev selection done; A staged (st==0)
    if (t < 256) XXS[t] = (float)xxd[b*N_ + m0 + t];

    // wave w consumes neighbor tile (m0>>5)+w; pages are contiguous per wave
    const short* Bp = Xs + (((size_t)b*64 + (m0 >> 5) + w) * 12) * 512 + lane*8;
    short8 b0 = *(const short8*)(Bp + 0*512);
    short8 b1 = *(const short8*)(Bp + 1*512);
    short8 c0 = *(const short8*)(Bp + 2*512);
    short8 c1 = *(const short8*)(Bp + 3*512);
    short8 d0 = *(const short8*)(Bp + 4*512);
    short8 d1 = *(const short8*)(Bp + 5*512);
    f32x16 acc = (f32x16)0.0f;
    #pragma unroll
    for (int kc = 0; kc < 6; ++kc){
      short8 a0 = *(const short8*)(smem + KLA + (kc*2+0)*1024 + lane*16);
      short8 a1 = *(const short8*)(smem + KLA + (kc*2+1)*1024 + lane*16);
      acc = __builtin_amdgcn_mfma_f32_32x32x16_bf16(a0, b0, acc, 0, 0, 0);
      acc = __builtin_amdgcn_mfma_f32_32x32x16_bf16(a1, b1, acc, 0, 0, 0);
      b0 = c0; b1 = c1; c0 = d0; c1 = d1;
      if (kc < 3){
        d0 = *(const short8*)(Bp + (kc*2+6)*512);
        d1 = *(const short8*)(Bp + (kc*2+7)*512);
      }
    }

    #pragma unroll
    for (int reg = 0; reg < 16; ++reg){
      int r = (reg & 3) + 8*(reg >> 2) + 4*lh;
      CT[r*260 + w*32 + l31] = acc[reg];
    }
    __syncthreads();

    {
      const int r = t & 31, sub = t >> 5;
      const float xn = XXN[r];
      const float* ctp = CT + r*260 + sub*16;
      const float* xsp = XXS + sub*16;
      const int mb = m0 + sub*16;
      #pragma unroll
      for (int q = 0; q < 4; ++q){
        float4 cv = *(const float4*)(ctp + 4*q);
        float4 xv = *(const float4*)(xsp + 4*q);
        float vs[4]  = {cv.x, cv.y, cv.z, cv.w};
        float xs4[4] = {xv.x, xv.y, xv.z, xv.w};
        #pragma unroll
        for (int j = 0; j < 4; ++j){
          float v = fmaf(2.f, vs[j], -(xs4[j] + xn));
          u32 bbits = __float_as_uint(v);
          u32 kk = ((bbits ^ (u32)(((int)bbits >> 31) | 0x80000000)) & 0xFFFFF800u)
                   | (u32)(mb + 4*q + j);
          #pragma unroll
          for (int s = 0; s < 9; ++s) key[s] = umin32(key[s+1], umax32(kk, key[s]));
          key[9] = umax32(kk, key[9]);
        }
      }
    }
  }

  // merge 16 sorted lists x 10 per row -> top-16 window (static indexing only)
  __syncthreads();
  u32* MVK = (u32*)(smem + KLCT);                 // 16*32*10*4 = 20,480
  {
    const int r = t & 31, sub = t >> 5;
    #pragma unroll
    for (int j = 0; j < 10; ++j) MVK[(sub*32 + r)*10 + j] = key[j];
  }
  __syncthreads();
  if (t < 32){
    int head[16];
    #pragma unroll
    for (int q = 0; q < 16; ++q) head[q] = 9;
    const size_t ob = ((size_t)b*N_ + n0 + t) * 16;
    for (int s = 0; s < 16; ++s){
      u32 best = 0u; int bq = 0;
      #pragma unroll
      for (int q = 0; q < 16; ++q){
        int hh = head[q];
        u32 v = (hh >= 0) ? MVK[(q*32 + t)*10 + hh] : 0u;
        if (v > best){ best = v; bq = q; }
      }
      cand[ob + s] = (u16)(best & 2047u);
      #pragma unroll
      for (int q = 0; q < 16; ++q) head[q] -= (q == bq) ? 1 : 0;
    }
  }
}

// ---------------- K1b: f64 refine, register-only, shuffle-rank top-11 ----------------
__global__ __launch_bounds__(256) void refine_kernel(const float* __restrict__ xT,
                                                     const u16* __restrict__ cand,
                                                     const double* __restrict__ xxd,
                                                     int* __restrict__ idxout){
  const int wv = threadIdx.x >> 6, ln = threadIdx.x & 63;
  const int g = blockIdx.x * 4 + wv;               // 0..16383
  const int b = g >> 11, n = g & 2047;
  const int c = ln >> 2, part = ln & 3;
  const int m = (int)cand[(size_t)g*16 + c] & 2047;
  const float4* pn = (const float4*)(xT + ((size_t)b*N_ + n)*192 + part*48);
  const float4* pm = (const float4*)(xT + ((size_t)b*N_ + m)*192 + part*48);
  double s = 0.0;
  #pragma unroll
  for (int j = 0; j < 12; ++j){                    // d ascending: same f64 order as before
    float4 a = pn[j], bb = pm[j];
    s = fma((double)a.x, (double)bb.x, s);
    s = fma((double)a.y, (double)bb.y, s);
    s = fma((double)a.z, (double)bb.z, s);
    s = fma((double)a.w, (double)bb.w, s);
  }
  s += __shfl_down(s, 2, 64);
  s += __shfl_down(s, 1, 64);                      // part==0 lanes hold full dot
  double v = 2.0*s - xxd[b*N_ + n] - xxd[b*N_ + m];
  int rank = 0;
  #pragma unroll
  for (int q = 0; q < 16; ++q){
    double vq = __shfl(v, q*4, 64);
    int    mq = __shfl(m, q*4, 64);
    bool beat = (vq > v) || ((vq == v) && (mq < m));
    rank += beat ? 1 : 0;
  }
  if (part == 0 && rank < KNb)
    idxout[(size_t)g*KNb + rank] = m;
}

// ---------------- K2: P0/D0 from xT, 16-pt tiles, natural VGPR ----------------
// Spill ledger: (256,4)->64-cap: 400MB scratch (R3/R5). (256,2)->128-cap: STILL
// ~230B/thread scratch (R2/R6). Natural footprint ~150 VGPR -> any cap <=128
// spills. Uncapped: zero scratch, 12 waves/CU (R7: 278us total, kernel left top-5).
__global__ __launch_bounds__(256) void project_kernel(const float* __restrict__ xT,
                                                      const float* __restrict__ Wf,
                                                      const float* __restrict__ Wd,
                                                      h4* __restrict__ P0h,
                                                      h4* __restrict__ D0h){
  __shared__ float A[16 * 192];                    // 12 KB, [m][e]
  const int b = blockIdx.x, m0 = blockIdx.y * 16, t = threadIdx.x;
  const int c = t & 63, mg = t >> 6;               // 4 groups of 4 points

  float wf[64], wd[64];
  #pragma unroll
  for (int q = 0; q < 16; ++q){
    float4 uf = *(const float4*)(Wf + c*64 + q*4);
    wf[q*4+0]=uf.x; wf[q*4+1]=uf.y; wf[q*4+2]=uf.z; wf[q*4+3]=uf.w;
    float4 ud = *(const float4*)(Wd + c*64 + q*4);
    wd[q*4+0]=ud.x; wd[q*4+1]=ud.y; wd[q*4+2]=ud.z; wd[q*4+3]=ud.w;
  }
  {
    const float4* src = (const float4*)(xT + ((size_t)b*N_ + m0)*192);
    float4* dst = (float4*)A;
    #pragma unroll
    for (int j = 0; j < 3; ++j) dst[t + 256*j] = src[t + 256*j];
  }
  __syncthreads();

  for (int mi = 0; mi < 4; ++mi){
    int m = mg*4 + mi;
    const float4* row = (const float4*)(A + m*192);
    float p[3] = {0.f,0.f,0.f}, qv[3] = {0.f,0.f,0.f};
    #pragma unroll
    for (int v4 = 0; v4 < 48; ++v4){
      float4 f = row[v4];
      const int e = v4*4;
      p [(e+0)%3] = fmaf(wf[(e+0)/3], f.x, p [(e+0)%3]);
      qv[(e+0)%3] = fmaf(wd[(e+0)/3], f.x, qv[(e+0)%3]);
      p [(e+1)%3] = fmaf(wf[(e+1)/3], f.y, p [(e+1)%3]);
      qv[(e+1)%3] = fmaf(wd[(e+1)/3], f.y, qv[(e+1)%3]);
      p [(e+2)%3] = fmaf(wf[(e+2)/3], f.z, p [(e+2)%3]);
      qv[(e+2)%3] = fmaf(wd[(e+2)/3], f.z, qv[(e+2)%3]);
      p [(e+3)%3] = fmaf(wf[(e+3)/3], f.w, p [(e+3)%3]);
      qv[(e+3)%3] = fmaf(wd[(e+3)/3], f.w, qv[(e+3)%3]);
    }
    float nrm = sqrtf(p[0]*p[0] + p[1]*p[1] + p[2]*p[2]);
    float dsq = qv[0]*qv[0] + qv[1]*qv[1] + qv[2]*qv[2];
    size_t base = ((size_t)b*N_ + m0 + m)*64 + c;
    h4 vp; vp.x = (f16)p[0];  vp.y = (f16)p[1];  vp.z = (f16)p[2];  vp.w = (f16)nrm;
    h4 vd; vd.x = (f16)qv[0]; vd.y = (f16)qv[1]; vd.z = (f16)qv[2]; vd.w = (f16)dsq;
    P0h[base] = vp;
    D0h[base] = vd;
  }
}

// ---------------- K3a: neighbor occurrence counts ----------------
__global__ __launch_bounds__(256) void count_kernel(const int* __restrict__ idxin, int* __restrict__ cnt){
  int i = blockIdx.x*256 + threadIdx.x;
  if (i < B_*N_*KNb){
    int b = i / (N_*KNb);
    atomicAdd(&cnt[b*N_ + (idxin[i] & 2047)], 1);
  }
}

// ---------------- K3b: per-channel weighted sum / sumsq of norms ----------------
__global__ __launch_bounds__(256) void stats_kernel(const h4* __restrict__ P0h,
                                                    const int* __restrict__ cnt,
                                                    float* __restrict__ gs){
  const int b = blockIdx.x >> 3;
  const int chunk = blockIdx.x & 7;
  const int w = threadIdx.x >> 6, c = threadIdx.x & 63;
  float s = 0.f, s2 = 0.f;
  const int mbase = chunk*256 + w*64;
  for (int i = 0; i < 64; ++i){
    int m = mbase + i;
    float wt = (float)cnt[b*N_ + m];
    float nv = (float)P0h[((size_t)b*N_ + m)*64 + c].w;
    s  = fmaf(wt, nv, s);
    s2 = fmaf(wt*nv, nv, s2);
  }
  __shared__ float red[8][64];
  red[w][c] = s; red[4+w][c] = s2;
  __syncthreads();
  if (w == 0) atomicAdd(&gs[c],    red[0][c]+red[1][c]+red[2][c]+red[3][c]);
  if (w == 1) atomicAdd(&gs[64+c], red[4][c]+red[5][c]+red[6][c]+red[7][c]);
}

// ---------------- K4: gather + BN + nonlinearity + mean over K ----------------
// R7 postmortem: grid (8,32) = 1 block/CU x 8 waves -> Occupancy 19%, VALUBusy 26%,
// latency-starved on L2 gathers (HBM 4.9%). Fix: 16-pt tiles (res 12.4KB LDS),
// grid (8,128) = 4 blocks/CU x 8 waves = 32 waves/CU (HW max). Same per-(n,c)
// arithmetic order -> bitwise-identical output.
__global__ __launch_bounds__(512) void out_kernel(const h4* __restrict__ P0h, const h4* __restrict__ D0h,
                                                  const int* __restrict__ idxin, const float* __restrict__ gs,
                                                  const float* __restrict__ gamma, const float* __restrict__ beta,
                                                  float* __restrict__ outp){
  __shared__ float res[16 * 193];                  // 12,352 B
  const int b  = blockIdx.x;
  const int n0 = blockIdx.y * 16;
  const int t = threadIdx.x, w = t >> 6, c = t & 63;
  const float Ninv = 1.f / (float)(B_*N_*KNb);
  float mean = gs[c] * Ninv;
  float var  = gs[64+c] * Ninv - mean*mean;
  float istd = rsqrtf(var + 1e-5f);
  float sa = istd * gamma[c];
  float be = beta[c];
  const float kinv = 1.f/11.f;
  for (int i = 0; i < 2; ++i){
    int row = w*2 + i;
    int n = n0 + row;
    const int* ip = idxin + ((size_t)b*N_ + n)*KNb;
    float a0=0, a1=0, a2=0;
    #pragma unroll
    for (int k = 0; k < KNb; ++k){
      int m = ip[k] & 2047;
      size_t base = ((size_t)b*N_ + m)*64 + c;
      h4 P  = P0h[base];
      h4 Dv = D0h[base];
      float pw = (float)P.w;
      float nb = (pw - mean)*sa + be;
      float sc = nb / pw;
      float p0 = (float)P.x*sc, p1 = (float)P.y*sc, p2 = (float)P.z*sc;
      float d0 = (float)Dv.x, d1 = (float)Dv.y, d2 = (float)Dv.z;
      float dot = p0*d0 + p1*d1 + p2*d2;
      float f = (dot >= 0.f) ? 0.f : dot / ((float)Dv.w + 1e-6f);
      a0 += p0 - f*d0; a1 += p1 - f*d1; a2 += p2 - f*d2;
    }
    res[row*193 + 3*c + 0] = a0*kinv;
    res[row*193 + 3*c + 1] = a1*kinv;
    res[row*193 + 3*c + 2] = a2*kinv;
  }
  __syncthreads();
  {
    int p = t;                                     // 768 float4 stores: 512 + 256
    #pragma unroll
    for (int j = 0; j < 2; ++j){
      if (p < 768){
        int cdim = p >> 2, nq = p & 3;
        float4 v = { res[(nq*4 + 0)*193 + cdim], res[(nq*4 + 1)*193 + cdim],
                     res[(nq*4 + 2)*193 + cdim], res[(nq*4 + 3)*193 + cdim] };
        *(float4*)(outp + ((size_t)b*192 + cdim)*N_ + n0 + nq*4) = v;
      }
      p += 512;
    }
  }
}

extern "C" void kernel_launch(void* const* d_in, const int* in_sizes, int n_in,
                              void* d_out, int out_size, void* d_ws, size_t ws_size,
                              hipStream_t stream){
  const float* x     = (const float*)d_in[0];
  const float* Wf    = (const float*)d_in[1];
  const float* Wd    = (const float*)d_in[2];
  const float* gamma = (const float*)d_in[3];
  const float* beta  = (const float*)d_in[4];
  float* outp = (float*)d_out;

  char* ws = (char*)d_ws;
  int*    idx  = (int*)   (ws);                 // 720,896
  int*    cnt  = (int*)   (ws + 720896);        // 65,536
  float*  gs   = (float*) (ws + 786432);        // 512
  h4*     P0h  = (h4*)    (ws + 1048576);       // 8,388,608
  h4*     D0h  = (h4*)    (ws + 9437184);       // 8,388,608 (ends 17,825,792)
  short*  Xs   = (short*) (ws + 1048576);       //   alias (6,291,456), consumed pre-project
  double* xxd  = (double*)(ws + 13631488);      //   alias (lives in D0h region pre-project)
  u16*    cand = (u16*)   (ws + 13762560);      //   alias
  float*  xT   = (float*) (ws + 17825792);      // 12,582,912 (ends 30,408,704)

  hipMemsetAsync(cnt, 0, 66048, stream);        // zero cnt + gs (contiguous)
  split_kernel  <<<dim3(32, 8),  256, 0, stream>>>(x, Xs, xT, xxd);
  knn_kernel    <<<dim3(8, 64),  512, 0, stream>>>(Xs, xxd, cand);
  refine_kernel <<<4096,         256, 0, stream>>>(xT, cand, xxd, idx);
  project_kernel<<<dim3(8, 128), 256, 0, stream>>>(xT, Wf, Wd, P0h, D0h);
  count_kernel  <<<704,          256, 0, stream>>>(idx, cnt);
  stats_kernel  <<<64,           256, 0, stream>>>(P0h, cnt, gs);
  out_kernel    <<<dim3(8, 128), 512, 0, stream>>>(P0h, D0h, idx, gs, gamma, beta, outp);
}